// Round 6
// baseline (300.103 us; speedup 1.0000x reference)
//
#include <hip/hip_runtime.h>
#include <hip/hip_bf16.h>

#define B_ 32
#define T_ 4096
#define H_ 512
#define MT 64          // M-tile rows (2 t x 32 b)
#define TPB 4          // tiles per block
#define NBLK 512       // blocks; NBLK*TPB*MT = 131072 rows
#define NTHREADS 512

typedef __attribute__((ext_vector_type(4))) short short4v;
typedef __attribute__((ext_vector_type(8))) __bf16 bf16x8;
typedef __attribute__((ext_vector_type(4))) float f32x4;

__device__ __forceinline__ short f2bf(float f) {
    unsigned u = __builtin_bit_cast(unsigned, f);
    u = (u + 0x7fffu + ((u >> 16) & 1u)) >> 16;
    return (short)u;
}

// ---- prep: W2 -> bf16 fragment-packed (IDENTICAL to R4/R5 verified layout) ----
// w2f[c][ck][ni][lane][j]: c=col block 0..7, ck=k-chunk 0..15 (32 k each), ni=0..3
// h = c*64+ni*16+(lane&15), k = ck*32+(lane>>4)*8+j
__global__ void prep_w2f(const float* __restrict__ W, short* __restrict__ w2f) {
    int idx = blockIdx.x * 256 + threadIdx.x;   // 0 .. 262143
    int j    = idx & 7;
    int lane = (idx >> 3) & 63;
    int ni   = (idx >> 9) & 3;
    int ck   = (idx >> 11) & 15;
    int c    = (idx >> 15) & 7;
    int h = c * 64 + ni * 16 + (lane & 15);
    int k = ck * 32 + (lane >> 4) * 8 + j;
    w2f[idx] = f2bf(W[h * (2 * H_) + H_ + k]);
}

// ---- prep: hid_proj[b][h] = hidden[b,:]*W1[h,:] + bias[h] (f32 exact) ----
__global__ void prep_hid(const float* __restrict__ hidden,
                         const float* __restrict__ W,
                         const float* __restrict__ bias,
                         float* __restrict__ hidproj) {
    __shared__ float hrow[H_];
    int b = blockIdx.y;
    int h = blockIdx.x * 128 + threadIdx.x;
    for (int i = threadIdx.x; i < H_; i += 128) hrow[i] = hidden[b * H_ + i];
    __syncthreads();
    const float* wr = W + (size_t)h * (2 * H_);
    float acc = bias[h];
#pragma unroll 4
    for (int k = 0; k < H_; k += 4) {
        acc += hrow[k]     * wr[k];
        acc += hrow[k + 1] * wr[k + 1];
        acc += hrow[k + 2] * wr[k + 2];
        acc += hrow[k + 3] * wr[k + 3];
    }
    hidproj[b * H_ + h] = acc;
}

// ---- main: full-K A tiles, dbuf, ONE barrier per M-tile ----
__global__ __launch_bounds__(NTHREADS, 2)
void attn_main(const float* __restrict__ enc,      // [T*B][H] f32
               const float* __restrict__ hidproj,  // [B][H] f32
               const short* __restrict__ w2f,      // frag-packed bf16 W2
               const float* __restrict__ vvec,     // [H]
               float* __restrict__ out)            // [B][T]
{
    __shared__ __align__(16) short lds_a[2][MT * H_];  // 2 x 64 KB
    __shared__ float red[2][NTHREADS];                  // 4 KB, tile-parity dbuf

    const int tid  = threadIdx.x;
    const int lane = tid & 63;
    const int wid  = tid >> 6;
    const int lo   = lane & 15;
    const int hi4  = lane >> 4;

    const int bid  = blockIdx.x;
    const int bswz = (bid & 7) * (NBLK / 8) + (bid >> 3);  // XCD swizzle, bijective
    const int gbase = bswz * TPB;

    // B stream base (wave wid owns h in [wid*64, wid*64+64))
    const short* wbase = w2f + (size_t)wid * 32768 + lane * 8;

    // A staging thread constants: per instr j, block covers rows [4j,4j+4) of tile
    const int th  = tid >> 7;              // 0..3 (row within 4-row group)
    const int gq  = (tid & 127) >> 1;      // 8-short group 0..63
    const int sub = (tid & 1) * 8;         // byte sub-offset within group
    const int gb2 = gq ^ ((gq >> 3) & 7) ^ th;
    const int wconst = th * 1024 + sub;    // byte
    const int aoff   = th * H_ + (tid & 127) * 4;  // f32

    float vh[4];
#pragma unroll
    for (int ni = 0; ni < 4; ++ni) vh[ni] = vvec[wid * 64 + ni * 16 + lo];

    // ---- prologue: stage tile gbase into buf 0 (exposed once) ----
    {
        const float* ap = enc + (size_t)gbase * (MT * H_) + aoff;
        f32x4 xs[16];
#pragma unroll
        for (int j = 0; j < 16; ++j) xs[j] = *(const f32x4*)(ap + j * 2048);
#pragma unroll
        for (int j = 0; j < 16; ++j) {
            short4v p;
            p[0] = f2bf(xs[j][0]); p[1] = f2bf(xs[j][1]);
            p[2] = f2bf(xs[j][2]); p[3] = f2bf(xs[j][3]);
            int gp = gb2 ^ ((j & 1) << 2);
            *(short4v*)((char*)&lds_a[0][0] + j * 4096 + wconst + gp * 16) = p;
        }
        asm volatile("s_waitcnt lgkmcnt(0)" ::: "memory");
        __builtin_amdgcn_s_barrier();
    }

    for (int lt = 0; lt < TPB; ++lt) {
        const int g   = gbase + lt;
        const int buf = lt & 1;
        const short* __restrict__ ab = &lds_a[buf][0];
        short* __restrict__ adst = &lds_a[buf ^ 1][0];
        const bool pf = (lt + 1) < TPB;

        f32x4 acc[4][4];
#pragma unroll
        for (int i = 0; i < 4; ++i)
#pragma unroll
            for (int j = 0; j < 4; ++j) acc[i][j] = f32x4{0.f, 0.f, 0.f, 0.f};

        // B ring prologue: chunks 0,1
        bf16x8 bq[3][4];
#pragma unroll
        for (int ni = 0; ni < 4; ++ni) bq[0][ni] = *(const bf16x8*)(wbase + (0 * 4 + ni) * 512);
#pragma unroll
        for (int ni = 0; ni < 4; ++ni) bq[1][ni] = *(const bf16x8*)(wbase + (1 * 4 + ni) * 512);

        f32x4 xs[16];
        const float* ap = enc + (size_t)(g + 1) * (MT * H_) + aoff;

#pragma unroll
        for (int c = 0; c < 16; ++c) {
            // issue next-tile A loads early (consumed ~8 chunks later)
            if (c == 0 && pf) {
#pragma unroll
                for (int j = 0; j < 16; ++j) xs[j] = *(const f32x4*)(ap + j * 2048);
            }
            // B prefetch distance 2
            if (c + 2 < 16) {
#pragma unroll
                for (int ni = 0; ni < 4; ++ni)
                    bq[(c + 2) % 3][ni] = *(const bf16x8*)(wbase + ((c + 2) * 4 + ni) * 512);
            }
            // A fragments from LDS (double-XOR swizzle, <=2-way banks)
            bf16x8 af[4];
#pragma unroll
            for (int mi = 0; mi < 4; ++mi) {
                int row = mi * 16 + lo;
                int gg  = c * 4 + hi4;
                int gp  = gg ^ ((gg >> 3) & 7) ^ (lo & 7);
                af[mi] = *(const bf16x8*)&ab[row * H_ + gp * 8];
            }
            __builtin_amdgcn_s_setprio(1);
#pragma unroll
            for (int mi = 0; mi < 4; ++mi)
#pragma unroll
                for (int ni = 0; ni < 4; ++ni)
                    acc[mi][ni] = __builtin_amdgcn_mfma_f32_16x16x32_bf16(
                        af[mi], bq[c % 3][ni], acc[mi][ni], 0, 0, 0);
            __builtin_amdgcn_s_setprio(0);
            // cvt + swizzled write of next-tile A, 4 groups per even chunk 8..14
            if (pf && c >= 8 && (c & 1) == 0) {
                const int j0 = ((c - 8) >> 1) << 2;
#pragma unroll
                for (int jj = 0; jj < 4; ++jj) {
                    const int j = j0 + jj;
                    short4v p;
                    p[0] = f2bf(xs[j][0]); p[1] = f2bf(xs[j][1]);
                    p[2] = f2bf(xs[j][2]); p[3] = f2bf(xs[j][3]);
                    int gp = gb2 ^ ((j & 1) << 2);
                    *(short4v*)((char*)adst + j * 4096 + wconst + gp * 16) = p;
                }
            }
        }

        // ---- per-tile epilogue: energy=acc+hid, softmax over b, v-dot, reduce ----
        {
            float hp[2][4][4];
#pragma unroll
            for (int par = 0; par < 2; ++par)
#pragma unroll
                for (int j = 0; j < 4; ++j) {
                    int b = par * 16 + hi4 * 4 + j;
#pragma unroll
                    for (int ni = 0; ni < 4; ++ni)
                        hp[par][j][ni] = hidproj[b * H_ + wid * 64 + ni * 16 + lo];
                }
#pragma unroll
            for (int mi = 0; mi < 4; ++mi)
#pragma unroll
                for (int ni = 0; ni < 4; ++ni)
#pragma unroll
                    for (int j = 0; j < 4; ++j)
                        acc[mi][ni][j] += hp[mi & 1][j][ni];
        }

        float scp[4][4];
#pragma unroll
        for (int tl2 = 0; tl2 < 2; ++tl2) {
            const int m0 = tl2 * 2, m1 = tl2 * 2 + 1;
#pragma unroll
            for (int ni = 0; ni < 4; ++ni) {
                float mx = -1e30f;
#pragma unroll
                for (int j = 0; j < 4; ++j) {
                    mx = fmaxf(mx, acc[m0][ni][j]);
                    mx = fmaxf(mx, acc[m1][ni][j]);
                }
                mx = fmaxf(mx, __shfl_xor(mx, 16));
                mx = fmaxf(mx, __shfl_xor(mx, 32));
                float e0[4], e1[4];
                float sum = 0.f;
#pragma unroll
                for (int j = 0; j < 4; ++j) {
                    e0[j] = __expf(acc[m0][ni][j] - mx);
                    e1[j] = __expf(acc[m1][ni][j] - mx);
                    sum += e0[j] + e1[j];
                }
                sum += __shfl_xor(sum, 16);
                sum += __shfl_xor(sum, 32);
                float rs = vh[ni] / sum;  // fold v[h] and 1/denom
#pragma unroll
                for (int j = 0; j < 4; ++j) {
                    if (ni == 0) { scp[m0][j] = e0[j] * rs; scp[m1][j] = e1[j] * rs; }
                    else         { scp[m0][j] += e0[j] * rs; scp[m1][j] += e1[j] * rs; }
                }
            }
        }

#pragma unroll
        for (int mi = 0; mi < 4; ++mi)
#pragma unroll
            for (int j = 0; j < 4; ++j) {
                float x = scp[mi][j];
                x += __shfl_xor(x, 1);
                x += __shfl_xor(x, 2);
                x += __shfl_xor(x, 4);
                x += __shfl_xor(x, 8);
                scp[mi][j] = x;
            }

        if (lo == 0) {
#pragma unroll
            for (int mi = 0; mi < 4; ++mi)
#pragma unroll
                for (int j = 0; j < 4; ++j)
                    red[buf][wid * 64 + mi * 16 + hi4 * 4 + j] = scp[mi][j];
        }
        // one barrier per tile: red visible + staged A(lt+1) visible
        asm volatile("s_waitcnt lgkmcnt(0)" ::: "memory");
        __builtin_amdgcn_s_barrier();

        if (tid < MT) {
            float s = 0.f;
#pragma unroll
            for (int w = 0; w < 8; ++w) s += red[buf][w * 64 + tid];
            int b   = tid & 31;
            int tl2 = tid >> 5;
            out[(size_t)b * T_ + (g * 2 + tl2)] = fmaxf(s, 0.f);
        }
    }
}

extern "C" void kernel_launch(void* const* d_in, const int* in_sizes, int n_in,
                              void* d_out, int out_size, void* d_ws, size_t ws_size,
                              hipStream_t stream) {
    const float* hidden = (const float*)d_in[0];
    const float* enc    = (const float*)d_in[1];
    const float* W      = (const float*)d_in[2];
    const float* bias   = (const float*)d_in[3];
    const float* v      = (const float*)d_in[4];
    float* out = (float*)d_out;

    float* hidproj = (float*)d_ws;                    // 64 KB
    short* w2f     = (short*)((char*)d_ws + 65536);   // 512 KB

    prep_w2f<<<1024, 256, 0, stream>>>(W, w2f);
    prep_hid<<<dim3(4, 32), 128, 0, stream>>>(hidden, W, bias, hidproj);
    attn_main<<<NBLK, NTHREADS, 0, stream>>>(enc, hidproj, w2f, v, out);
}

// Round 7
// 232.914 us; speedup vs baseline: 1.2885x; 1.2885x over previous
//
#include <hip/hip_runtime.h>
#include <hip/hip_bf16.h>

#define B_ 32
#define T_ 4096
#define H_ 512
#define TILE_T 4
#define M_TILE 128   // TILE_T * B_
#define BK 128
#define KSTEPS 4     // H_ / BK
#define NTHREADS 512

typedef __attribute__((ext_vector_type(8))) short short8;
typedef __attribute__((ext_vector_type(8))) __bf16 bf16x8;
typedef __attribute__((ext_vector_type(4))) float f32x4;

__device__ __forceinline__ short f2bf(float f) {
    unsigned u = __builtin_bit_cast(unsigned, f);
    u = (u + 0x7fffu + ((u >> 16) & 1u)) >> 16;
    return (short)u;
}

// hardware packed f32->bf16 (RNE), 2 elems per instruction
__device__ __forceinline__ short8 pack8(f32x4 a, f32x4 b) {
    union { unsigned u[4]; short8 s; } r;
    asm("v_cvt_pk_bf16_f32 %0, %1, %2" : "=v"(r.u[0]) : "v"(a[0]), "v"(a[1]));
    asm("v_cvt_pk_bf16_f32 %0, %1, %2" : "=v"(r.u[1]) : "v"(a[2]), "v"(a[3]));
    asm("v_cvt_pk_bf16_f32 %0, %1, %2" : "=v"(r.u[2]) : "v"(b[0]), "v"(b[1]));
    asm("v_cvt_pk_bf16_f32 %0, %1, %2" : "=v"(r.u[3]) : "v"(b[2]), "v"(b[3]));
    return r.s;
}

// ---- prep: W2 -> bf16 fragment-packed (R6-verified layout) ----
// w2f[c][ck][ni][lane][j]: c=col block 0..7, ck=k-chunk-of-32 0..15, ni=0..3
// h = c*64+ni*16+(lane&15), k = ck*32+(lane>>4)*8+j
__global__ void prep_w2f(const float* __restrict__ W, short* __restrict__ w2f) {
    int idx = blockIdx.x * 256 + threadIdx.x;   // 0 .. 262143
    int j    = idx & 7;
    int lane = (idx >> 3) & 63;
    int ni   = (idx >> 9) & 3;
    int ck   = (idx >> 11) & 15;
    int c    = (idx >> 15) & 7;
    int h = c * 64 + ni * 16 + (lane & 15);
    int k = ck * 32 + (lane >> 4) * 8 + j;
    w2f[idx] = f2bf(W[h * (2 * H_) + H_ + k]);
}

// ---- prep: hid_proj[b][h] = hidden[b,:]*W1[h,:] + bias[h] (f32 exact) ----
__global__ void prep_hid(const float* __restrict__ hidden,
                         const float* __restrict__ W,
                         const float* __restrict__ bias,
                         float* __restrict__ hidproj) {
    __shared__ float hrow[H_];
    int b = blockIdx.y;
    int h = blockIdx.x * 128 + threadIdx.x;
    for (int i = threadIdx.x; i < H_; i += 128) hrow[i] = hidden[b * H_ + i];
    __syncthreads();
    const float* wr = W + (size_t)h * (2 * H_);
    float acc = bias[h];
#pragma unroll 4
    for (int k = 0; k < H_; k += 4) {
        acc += hrow[k]     * wr[k];
        acc += hrow[k + 1] * wr[k + 1];
        acc += hrow[k + 2] * wr[k + 2];
        acc += hrow[k + 3] * wr[k + 3];
    }
    hidproj[b * H_ + h] = acc;
}

// ---- main: BK=128, A-only LDS dbuf, 1 barrier per kstep (4 total) ----
__global__ __launch_bounds__(NTHREADS, 2)
void attn_main(const float* __restrict__ enc,      // [T*B][H] f32
               const float* __restrict__ hidproj,  // [B][H] f32
               const short* __restrict__ w2f,      // frag-packed bf16 W2
               const float* __restrict__ vvec,     // [H]
               float* __restrict__ out)            // [B][T]
{
    __shared__ __align__(16) short lds_a[2][M_TILE * BK];  // 2 x 32 KB

    const int tid  = threadIdx.x;
    const int lane = tid & 63;
    const int wid  = tid >> 6;
    const int t0   = blockIdx.x * TILE_T;
    const int n0   = wid * 64;
    const int lo   = lane & 15;
    const int hi4  = lane >> 4;

    f32x4 acc[8][4];
#pragma unroll
    for (int i = 0; i < 8; ++i)
#pragma unroll
        for (int j = 0; j < 4; ++j) acc[i][j] = f32x4{0.f, 0.f, 0.f, 0.f};

    // B stream: wave wid owns h in [wid*64, wid*64+64); frag (ck,ni) at (ck*4+ni)*512
    const short* wbase = w2f + (size_t)wid * 32768 + lane * 8;

    // A staging map: thread -> row = tid>>2 (0..127), akc = tid&3 (32 f32 each)
    const int arow = tid >> 2;
    const int akc  = tid & 3;
    const float* abase = enc + (size_t)(t0 * B_ + arow) * H_ + akc * 32;
    // 4 bf16-chunk write slots (chunks akc*4+q, XOR row&7), b128 each
    const int aw0 = arow * BK + (((akc * 4 + 0) ^ (arow & 7)) << 3);
    const int aw1 = arow * BK + (((akc * 4 + 1) ^ (arow & 7)) << 3);
    const int aw2 = arow * BK + (((akc * 4 + 2) ^ (arow & 7)) << 3);
    const int aw3 = arow * BK + (((akc * 4 + 3) ^ (arow & 7)) << 3);

    // ---- prologue: stage A(kstep 0) into lds_a[0] ----
    {
        f32x4 y0 = *(const f32x4*)(abase);      f32x4 y1 = *(const f32x4*)(abase + 4);
        f32x4 y2 = *(const f32x4*)(abase + 8);  f32x4 y3 = *(const f32x4*)(abase + 12);
        f32x4 y4 = *(const f32x4*)(abase + 16); f32x4 y5 = *(const f32x4*)(abase + 20);
        f32x4 y6 = *(const f32x4*)(abase + 24); f32x4 y7 = *(const f32x4*)(abase + 28);
        *(short8*)&lds_a[0][aw0] = pack8(y0, y1);
        *(short8*)&lds_a[0][aw1] = pack8(y2, y3);
        *(short8*)&lds_a[0][aw2] = pack8(y4, y5);
        *(short8*)&lds_a[0][aw3] = pack8(y6, y7);
        asm volatile("s_waitcnt lgkmcnt(0)" ::: "memory");
        __builtin_amdgcn_s_barrier();
    }

    // per-ksub compute: 8 mi frags (two passes of 4) x 4 ni, 32 MFMA
#define KSUB(S, BQ)                                                               \
    {                                                                             \
        bf16x8 af[4];                                                             \
        _Pragma("unroll")                                                         \
        for (int mi = 0; mi < 4; ++mi) {                                          \
            int r = mi * 16 + lo;                                                 \
            af[mi] = *(const bf16x8*)&ab[r * BK + ((((S) * 4 + hi4) ^ (r & 7)) << 3)]; \
        }                                                                         \
        __builtin_amdgcn_s_setprio(1);                                            \
        _Pragma("unroll")                                                         \
        for (int mi = 0; mi < 4; ++mi)                                            \
            _Pragma("unroll")                                                     \
            for (int ni = 0; ni < 4; ++ni)                                        \
                acc[mi][ni] = __builtin_amdgcn_mfma_f32_16x16x32_bf16(            \
                    af[mi], BQ[ni], acc[mi][ni], 0, 0, 0);                        \
        __builtin_amdgcn_s_setprio(0);                                            \
        _Pragma("unroll")                                                         \
        for (int mi = 0; mi < 4; ++mi) {                                          \
            int r = (mi + 4) * 16 + lo;                                           \
            af[mi] = *(const bf16x8*)&ab[r * BK + ((((S) * 4 + hi4) ^ (r & 7)) << 3)]; \
        }                                                                         \
        __builtin_amdgcn_s_setprio(1);                                            \
        _Pragma("unroll")                                                         \
        for (int mi = 0; mi < 4; ++mi)                                            \
            _Pragma("unroll")                                                     \
            for (int ni = 0; ni < 4; ++ni)                                        \
                acc[mi + 4][ni] = __builtin_amdgcn_mfma_f32_16x16x32_bf16(        \
                    af[mi], BQ[ni], acc[mi + 4][ni], 0, 0, 0);                    \
        __builtin_amdgcn_s_setprio(0);                                            \
    }

#pragma unroll 1
    for (int kk = 0; kk < KSTEPS; ++kk) {
        const int cur = kk & 1;
        const bool pf = (kk + 1) < KSTEPS;
        const short* __restrict__ ab = &lds_a[cur][0];
        short* __restrict__ adst = &lds_a[cur ^ 1][0];

        // ---- issue A(kk+1) loads first (HBM long pole; consumed ~2 ksubs later) ----
        f32x4 x0, x1, x2, x3, x4, x5, x6, x7;
        if (pf) {
            const float* asrc = abase + (size_t)(kk + 1) * BK;
            x0 = *(const f32x4*)(asrc);      x1 = *(const f32x4*)(asrc + 4);
            x2 = *(const f32x4*)(asrc + 8);  x3 = *(const f32x4*)(asrc + 12);
            x4 = *(const f32x4*)(asrc + 16); x5 = *(const f32x4*)(asrc + 20);
            x6 = *(const f32x4*)(asrc + 24); x7 = *(const f32x4*)(asrc + 28);
        }

        // ---- B ring: 2-deep named ring over the 4 ksubs of this kstep ----
        const int ck0 = kk * 4;
        bf16x8 bqA[4], bqB[4];
#pragma unroll
        for (int ni = 0; ni < 4; ++ni) bqA[ni] = *(const bf16x8*)(wbase + ((ck0 + 0) * 4 + ni) * 512);
#pragma unroll
        for (int ni = 0; ni < 4; ++ni) bqB[ni] = *(const bf16x8*)(wbase + ((ck0 + 1) * 4 + ni) * 512);

        KSUB(0, bqA)
#pragma unroll
        for (int ni = 0; ni < 4; ++ni) bqA[ni] = *(const bf16x8*)(wbase + ((ck0 + 2) * 4 + ni) * 512);
        KSUB(1, bqB)
#pragma unroll
        for (int ni = 0; ni < 4; ++ni) bqB[ni] = *(const bf16x8*)(wbase + ((ck0 + 3) * 4 + ni) * 512);

        // ---- cvt + swizzled b128 writes of A(kk+1) into the idle buffer ----
        if (pf) {
            *(short8*)&adst[aw0] = pack8(x0, x1);
            *(short8*)&adst[aw1] = pack8(x2, x3);
            *(short8*)&adst[aw2] = pack8(x4, x5);
            *(short8*)&adst[aw3] = pack8(x6, x7);
        }

        KSUB(2, bqA)
        KSUB(3, bqB)

        // ---- single barrier per kstep: staged A(kk+1) visible to all waves ----
        asm volatile("s_waitcnt lgkmcnt(0)" ::: "memory");
        __builtin_amdgcn_s_barrier();
    }
#undef KSUB

    // ---- epilogue (verified R1-R5): energy += hidproj, softmax over b, v-dot ----
    {
        float hp[2][4][4];
#pragma unroll
        for (int par = 0; par < 2; ++par)
#pragma unroll
            for (int j = 0; j < 4; ++j) {
                int b = par * 16 + hi4 * 4 + j;
#pragma unroll
                for (int ni = 0; ni < 4; ++ni)
                    hp[par][j][ni] = hidproj[b * H_ + n0 + ni * 16 + lo];
            }
#pragma unroll
        for (int mi = 0; mi < 8; ++mi)
#pragma unroll
            for (int ni = 0; ni < 4; ++ni)
#pragma unroll
                for (int j = 0; j < 4; ++j)
                    acc[mi][ni][j] += hp[mi & 1][j][ni];
    }

    float vh[4];
#pragma unroll
    for (int ni = 0; ni < 4; ++ni) vh[ni] = vvec[n0 + ni * 16 + lo];

    float scp[8][4];
#pragma unroll
    for (int tl = 0; tl < 4; ++tl) {
        const int m0 = tl * 2, m1 = tl * 2 + 1;
#pragma unroll
        for (int ni = 0; ni < 4; ++ni) {
            float mx = -1e30f;
#pragma unroll
            for (int j = 0; j < 4; ++j) {
                mx = fmaxf(mx, acc[m0][ni][j]);
                mx = fmaxf(mx, acc[m1][ni][j]);
            }
            mx = fmaxf(mx, __shfl_xor(mx, 16));
            mx = fmaxf(mx, __shfl_xor(mx, 32));
            float e0[4], e1[4];
            float sum = 0.f;
#pragma unroll
            for (int j = 0; j < 4; ++j) {
                e0[j] = __expf(acc[m0][ni][j] - mx);
                e1[j] = __expf(acc[m1][ni][j] - mx);
                sum += e0[j] + e1[j];
            }
            sum += __shfl_xor(sum, 16);
            sum += __shfl_xor(sum, 32);
            float rs = vh[ni] / sum;  // fold v[h] and 1/denom
#pragma unroll
            for (int j = 0; j < 4; ++j) {
                if (ni == 0) { scp[m0][j] = e0[j] * rs; scp[m1][j] = e1[j] * rs; }
                else         { scp[m0][j] += e0[j] * rs; scp[m1][j] += e1[j] * rs; }
            }
        }
    }

#pragma unroll
    for (int mi = 0; mi < 8; ++mi)
#pragma unroll
        for (int j = 0; j < 4; ++j) {
            float x = scp[mi][j];
            x += __shfl_xor(x, 1);
            x += __shfl_xor(x, 2);
            x += __shfl_xor(x, 4);
            x += __shfl_xor(x, 8);
            scp[mi][j] = x;
        }

    __syncthreads();
    float* red = (float*)&lds_a[0][0];   // 4 KB reuse
    if (lo == 0) {
#pragma unroll
        for (int mi = 0; mi < 8; ++mi)
#pragma unroll
            for (int j = 0; j < 4; ++j)
                red[wid * 128 + mi * 16 + hi4 * 4 + j] = scp[mi][j];
    }
    __syncthreads();
    if (tid < 128) {
        float s = 0.f;
#pragma unroll
        for (int w = 0; w < 8; ++w) s += red[w * 128 + tid];
        int b  = tid & 31;
        int tl = tid >> 5;
        out[(size_t)b * T_ + (t0 + tl)] = fmaxf(s, 0.f);
    }
}

extern "C" void kernel_launch(void* const* d_in, const int* in_sizes, int n_in,
                              void* d_out, int out_size, void* d_ws, size_t ws_size,
                              hipStream_t stream) {
    const float* hidden = (const float*)d_in[0];
    const float* enc    = (const float*)d_in[1];
    const float* W      = (const float*)d_in[2];
    const float* bias   = (const float*)d_in[3];
    const float* v      = (const float*)d_in[4];
    float* out = (float*)d_out;

    float* hidproj = (float*)d_ws;                    // 64 KB
    short* w2f     = (short*)((char*)d_ws + 65536);   // 512 KB

    prep_w2f<<<1024, 256, 0, stream>>>(W, w2f);
    prep_hid<<<dim3(4, 32), 128, 0, stream>>>(hidden, W, bias, hidproj);
    attn_main<<<T_ / TILE_T, NTHREADS, 0, stream>>>(enc, hidproj, w2f, v, out);
}

// Round 8
// 121.238 us; speedup vs baseline: 2.4753x; 1.9211x over previous
//
#include <hip/hip_runtime.h>
#include <hip/hip_bf16.h>

#define B_ 32
#define T_ 4096
#define H_ 512
#define TILE_T 2
#define M_TILE 64    // TILE_T * B_
#define BK 64
#define KSTEPS 8     // H_ / BK
#define NTHREADS 256 // 4 waves; target 3 blocks/CU

typedef __attribute__((ext_vector_type(8))) short short8;
typedef __attribute__((ext_vector_type(8))) __bf16 bf16x8;
typedef __attribute__((ext_vector_type(4))) float f32x4;

__device__ __forceinline__ short f2bf(float f) {
    unsigned u = __builtin_bit_cast(unsigned, f);
    u = (u + 0x7fffu + ((u >> 16) & 1u)) >> 16;
    return (short)u;
}

// hardware packed f32->bf16 (RNE), 2 elems per instruction
__device__ __forceinline__ short8 pack8(f32x4 a, f32x4 b) {
    union { unsigned u[4]; short8 s; } r;
    asm("v_cvt_pk_bf16_f32 %0, %1, %2" : "=v"(r.u[0]) : "v"(a[0]), "v"(a[1]));
    asm("v_cvt_pk_bf16_f32 %0, %1, %2" : "=v"(r.u[1]) : "v"(a[2]), "v"(a[3]));
    asm("v_cvt_pk_bf16_f32 %0, %1, %2" : "=v"(r.u[2]) : "v"(b[0]), "v"(b[1]));
    asm("v_cvt_pk_bf16_f32 %0, %1, %2" : "=v"(r.u[3]) : "v"(b[2]), "v"(b[3]));
    return r.s;
}

// ---- prep: W2 -> bf16 fragment-packed (verified layout, unchanged) ----
// w2f[c][ck][ni][lane][j]: c=col block 0..7, ck=k-chunk-of-32 0..15, ni=0..3
// h = c*64+ni*16+(lane&15), k = ck*32+(lane>>4)*8+j
__global__ void prep_w2f(const float* __restrict__ W, short* __restrict__ w2f) {
    int idx = blockIdx.x * 256 + threadIdx.x;   // 0 .. 262143
    int j    = idx & 7;
    int lane = (idx >> 3) & 63;
    int ni   = (idx >> 9) & 3;
    int ck   = (idx >> 11) & 15;
    int c    = (idx >> 15) & 7;
    int h = c * 64 + ni * 16 + (lane & 15);
    int k = ck * 32 + (lane >> 4) * 8 + j;
    w2f[idx] = f2bf(W[h * (2 * H_) + H_ + k]);
}

// ---- prep: hid_proj[b][h] = hidden[b,:]*W1[h,:] + bias[h] (f32 exact) ----
__global__ void prep_hid(const float* __restrict__ hidden,
                         const float* __restrict__ W,
                         const float* __restrict__ bias,
                         float* __restrict__ hidproj) {
    __shared__ float hrow[H_];
    int b = blockIdx.y;
    int h = blockIdx.x * 128 + threadIdx.x;
    for (int i = threadIdx.x; i < H_; i += 128) hrow[i] = hidden[b * H_ + i];
    __syncthreads();
    const float* wr = W + (size_t)h * (2 * H_);
    float acc = bias[h];
#pragma unroll 4
    for (int k = 0; k < H_; k += 4) {
        acc += hrow[k]     * wr[k];
        acc += hrow[k + 1] * wr[k + 1];
        acc += hrow[k + 2] * wr[k + 2];
        acc += hrow[k + 3] * wr[k + 3];
    }
    hidproj[b * H_ + h] = acc;
}

// ---- finisher: out[b,t] = relu(sp0 + sp1) ----
__global__ void finish(const float* __restrict__ sp, float* __restrict__ out) {
    int i = blockIdx.x * 256 + threadIdx.x;   // 0 .. 131071
    out[i] = fmaxf(sp[i] + sp[131072 + i], 0.f);
}

// ---- main: 4-wave blocks, 64x256 per block (h-split), acc=64 -> 3 blocks/CU ----
__global__ __launch_bounds__(NTHREADS, 3)
void attn_main(const float* __restrict__ enc,      // [T*B][H] f32
               const float* __restrict__ hidproj,  // [B][H] f32
               const short* __restrict__ w2f,      // frag-packed bf16 W2
               const float* __restrict__ vvec,     // [H]
               float* __restrict__ spart)          // [2][B*T] partial scores
{
    __shared__ __align__(16) short lds_a[2][M_TILE * BK];  // 2 x 8 KB

    const int tid  = threadIdx.x;
    const int lane = tid & 63;
    const int wid  = tid >> 6;          // 0..3
    const int bid  = blockIdx.x;
    // eta-pair of same tau adjacent in dispatch mod 8 -> same XCD (L2 A-tile share)
    const int tau  = ((bid >> 4) << 3) | (bid & 7);   // 0..2047
    const int eta  = (bid >> 3) & 1;                  // 0..1
    const int t0   = tau * TILE_T;
    const int lo   = lane & 15;
    const int hi4  = lane >> 4;
    const int cblk = eta * 4 + wid;     // col block 0..7 (64 h each)

    f32x4 acc[4][4];
#pragma unroll
    for (int i = 0; i < 4; ++i)
#pragma unroll
        for (int j = 0; j < 4; ++j) acc[i][j] = f32x4{0.f, 0.f, 0.f, 0.f};

    const short* wbase = w2f + (size_t)cblk * 32768 + lane * 8;

    // A staging: thread -> row = tid>>2 (0..63), akc = tid&3 (16 f32 each)
    const int arow = tid >> 2;
    const int akc  = tid & 3;
    const float* abase = enc + (size_t)(t0 * B_ + arow) * H_ + akc * 16;
    const int aw0 = arow * BK + (((2 * akc)     ^ (arow & 7)) << 3);
    const int aw1 = arow * BK + (((2 * akc + 1) ^ (arow & 7)) << 3);

    // ---- prologue: stage A(0) into lds_a[0] ----
    {
        f32x4 y0 = *(const f32x4*)(abase);     f32x4 y1 = *(const f32x4*)(abase + 4);
        f32x4 y2 = *(const f32x4*)(abase + 8); f32x4 y3 = *(const f32x4*)(abase + 12);
        *(short8*)&lds_a[0][aw0] = pack8(y0, y1);
        *(short8*)&lds_a[0][aw1] = pack8(y2, y3);
        asm volatile("s_waitcnt lgkmcnt(0)" ::: "memory");
        __builtin_amdgcn_s_barrier();
    }

    // per-ksub: 4 mi frags x 4 ni, 16 MFMA
#define KSUB(S, BQ)                                                               \
    {                                                                             \
        bf16x8 af[4];                                                             \
        _Pragma("unroll")                                                         \
        for (int mi = 0; mi < 4; ++mi) {                                          \
            int r = mi * 16 + lo;                                                 \
            af[mi] = *(const bf16x8*)&ab[r * BK + ((((S) * 4 + hi4) ^ (r & 7)) << 3)]; \
        }                                                                         \
        __builtin_amdgcn_s_setprio(1);                                            \
        _Pragma("unroll")                                                         \
        for (int mi = 0; mi < 4; ++mi)                                            \
            _Pragma("unroll")                                                     \
            for (int ni = 0; ni < 4; ++ni)                                        \
                acc[mi][ni] = __builtin_amdgcn_mfma_f32_16x16x32_bf16(            \
                    af[mi], BQ[ni], acc[mi][ni], 0, 0, 0);                        \
        __builtin_amdgcn_s_setprio(0);                                            \
    }

#pragma unroll 1
    for (int kk = 0; kk < KSTEPS; ++kk) {
        const int cur = kk & 1;
        const bool pf = (kk + 1) < KSTEPS;
        const short* __restrict__ ab = &lds_a[cur][0];
        short* __restrict__ adst = &lds_a[cur ^ 1][0];

        // B frags for this kstep (L2, coalesced 16B/lane); ksub chunks ck = kk*2, kk*2+1
        bf16x8 b0[4], b1[4];
#pragma unroll
        for (int ni = 0; ni < 4; ++ni) b0[ni] = *(const bf16x8*)(wbase + ((kk * 2 + 0) * 4 + ni) * 512);
#pragma unroll
        for (int ni = 0; ni < 4; ++ni) b1[ni] = *(const bf16x8*)(wbase + ((kk * 2 + 1) * 4 + ni) * 512);

        // A(kk+1) loads (HBM; consumed after ksub0 / ksub1)
        f32x4 x0, x1, x2, x3;
        if (pf) {
            const float* asrc = abase + (size_t)(kk + 1) * BK;
            x0 = *(const f32x4*)(asrc);      x1 = *(const f32x4*)(asrc + 4);
            x2 = *(const f32x4*)(asrc + 8);  x3 = *(const f32x4*)(asrc + 12);
        }

        KSUB(0, b0)
        if (pf) *(short8*)&adst[aw0] = pack8(x0, x1);
        KSUB(1, b1)
        if (pf) *(short8*)&adst[aw1] = pack8(x2, x3);

        asm volatile("s_waitcnt lgkmcnt(0)" ::: "memory");
        __builtin_amdgcn_s_barrier();
    }
#undef KSUB

    // ---- epilogue: energy += hidproj, softmax over b, v-dot partials ----
    {
        float hp[2][4][4];
#pragma unroll
        for (int par = 0; par < 2; ++par)
#pragma unroll
            for (int j = 0; j < 4; ++j) {
                int b = par * 16 + hi4 * 4 + j;
#pragma unroll
                for (int ni = 0; ni < 4; ++ni)
                    hp[par][j][ni] = hidproj[b * H_ + cblk * 64 + ni * 16 + lo];
            }
#pragma unroll
        for (int mi = 0; mi < 4; ++mi)
#pragma unroll
            for (int ni = 0; ni < 4; ++ni)
#pragma unroll
                for (int j = 0; j < 4; ++j)
                    acc[mi][ni][j] += hp[mi & 1][j][ni];
    }

    float vh[4];
#pragma unroll
    for (int ni = 0; ni < 4; ++ni) vh[ni] = vvec[cblk * 64 + ni * 16 + lo];

    float scp[4][4];
#pragma unroll
    for (int tl2 = 0; tl2 < 2; ++tl2) {
        const int m0 = tl2 * 2, m1 = tl2 * 2 + 1;
#pragma unroll
        for (int ni = 0; ni < 4; ++ni) {
            float mx = -1e30f;
#pragma unroll
            for (int j = 0; j < 4; ++j) {
                mx = fmaxf(mx, acc[m0][ni][j]);
                mx = fmaxf(mx, acc[m1][ni][j]);
            }
            mx = fmaxf(mx, __shfl_xor(mx, 16));
            mx = fmaxf(mx, __shfl_xor(mx, 32));
            float e0[4], e1[4];
            float sum = 0.f;
#pragma unroll
            for (int j = 0; j < 4; ++j) {
                e0[j] = __expf(acc[m0][ni][j] - mx);
                e1[j] = __expf(acc[m1][ni][j] - mx);
                sum += e0[j] + e1[j];
            }
            sum += __shfl_xor(sum, 16);
            sum += __shfl_xor(sum, 32);
            float rs = vh[ni] / sum;  // fold v[h] and 1/denom
#pragma unroll
            for (int j = 0; j < 4; ++j) {
                if (ni == 0) { scp[m0][j] = e0[j] * rs; scp[m1][j] = e1[j] * rs; }
                else         { scp[m0][j] += e0[j] * rs; scp[m1][j] += e1[j] * rs; }
            }
        }
    }

#pragma unroll
    for (int mi = 0; mi < 4; ++mi)
#pragma unroll
        for (int j = 0; j < 4; ++j) {
            float x = scp[mi][j];
            x += __shfl_xor(x, 1);
            x += __shfl_xor(x, 2);
            x += __shfl_xor(x, 4);
            x += __shfl_xor(x, 8);
            scp[mi][j] = x;
        }

    __syncthreads();
    float* red = (float*)&lds_a[0][0];   // [4][64] = 1 KB reuse
    if (lo == 0) {
#pragma unroll
        for (int mi = 0; mi < 4; ++mi)
#pragma unroll
            for (int j = 0; j < 4; ++j)
                red[wid * 64 + mi * 16 + hi4 * 4 + j] = scp[mi][j];
    }
    __syncthreads();
    if (tid < M_TILE) {
        float s = red[tid] + red[64 + tid] + red[128 + tid] + red[192 + tid];
        int b   = tid & 31;
        int tl2 = tid >> 5;
        spart[(size_t)eta * 131072 + (size_t)b * T_ + (t0 + tl2)] = s;
    }
}

extern "C" void kernel_launch(void* const* d_in, const int* in_sizes, int n_in,
                              void* d_out, int out_size, void* d_ws, size_t ws_size,
                              hipStream_t stream) {
    const float* hidden = (const float*)d_in[0];
    const float* enc    = (const float*)d_in[1];
    const float* W      = (const float*)d_in[2];
    const float* bias   = (const float*)d_in[3];
    const float* v      = (const float*)d_in[4];
    float* out = (float*)d_out;

    float* hidproj = (float*)d_ws;                           // 64 KB
    short* w2f     = (short*)((char*)d_ws + 65536);          // 512 KB
    float* spart   = (float*)((char*)d_ws + 65536 + 524288); // 1 MB

    prep_w2f<<<1024, 256, 0, stream>>>(W, w2f);
    prep_hid<<<dim3(4, 32), 128, 0, stream>>>(hidden, W, bias, hidproj);
    attn_main<<<4096, NTHREADS, 0, stream>>>(enc, hidproj, w2f, v, spart);
    finish<<<512, 256, 0, stream>>>(spart, out);
}